// Round 1
// baseline (125.898 us; speedup 1.0000x reference)
//
#include <hip/hip_runtime.h>

// Problem constants (frozen in the reference)
#define RAD   4
#define KS    9          // kernel size 2R+1
#define HALO  8          // 2*RAD
#define SS    17         // KS + 2*RAD (staged neighborhood per dim)
#define DIM   256        // volume is 256^3
#define SIG   1.2f

// ---------------------------------------------------------------------------
// Kernel 1: vectorized copy volume -> out (float4, grid-stride)
// ---------------------------------------------------------------------------
__global__ __launch_bounds__(256) void copy_vol_kernel(
    const float4* __restrict__ in, float4* __restrict__ out, int n4) {
    int stride = gridDim.x * blockDim.x;
    for (int i = blockIdx.x * blockDim.x + threadIdx.x; i < n4; i += stride) {
        out[i] = in[i];
    }
}

// ---------------------------------------------------------------------------
// Kernel 2: per-point blur fix-up. One block per point.
//   Stage 17^3 neighborhood (zero-filled OOB, = zero-padded conv), then
//   separable z/y/x Gaussian passes in LDS, write clipped 9^3 outputs.
//   Overlapping boxes write bitwise-identical values -> benign.
// ---------------------------------------------------------------------------
__global__ __launch_bounds__(256) void blur_fix_kernel(
    const float* __restrict__ vol, const int* __restrict__ pts,
    float* __restrict__ out) {
    __shared__ float sm[SS * SS * SS];   // 4913 floats
    __shared__ float t1[KS * SS * SS];   // z-blurred: 9 x 17 x 17
    __shared__ float t2[KS * KS * SS];   // z+y-blurred: 9 x 9 x 17

    const int p  = blockIdx.x;
    const int tid = threadIdx.x;
    const int pz = pts[3 * p + 0];
    const int py = pts[3 * p + 1];
    const int px = pts[3 * p + 2];

    // Gaussian weights (normalized), same arithmetic as reference (fp32 exp)
    float g[KS];
    {
        float s = 0.f;
        #pragma unroll
        for (int i = 0; i < KS; ++i) {
            float x = (float)(i - RAD);
            g[i] = expf(-(x * x) / (2.f * SIG * SIG));
            s += g[i];
        }
        float inv = 1.f / s;
        #pragma unroll
        for (int i = 0; i < KS; ++i) g[i] *= inv;
    }

    // Stage 17^3 neighborhood centered at point, zeros outside the volume
    for (int idx = tid; idx < SS * SS * SS; idx += 256) {
        int k = idx % SS;
        int j = (idx / SS) % SS;
        int i = idx / (SS * SS);
        int z = pz - HALO + i;
        int y = py - HALO + j;
        int x = px - HALO + k;
        float v = 0.f;
        if ((unsigned)z < (unsigned)DIM && (unsigned)y < (unsigned)DIM &&
            (unsigned)x < (unsigned)DIM) {
            v = vol[((z * DIM) + y) * DIM + x];
        }
        sm[idx] = v;
    }
    __syncthreads();

    // Pass 1: blur along z.  Output i in [0,9) maps to z = pz - RAD + i.
    for (int idx = tid; idx < KS * SS * SS; idx += 256) {
        int k = idx % SS;
        int j = (idx / SS) % SS;
        int i = idx / (SS * SS);
        float acc = 0.f;
        #pragma unroll
        for (int t = 0; t < KS; ++t)
            acc += g[t] * sm[(((i + t) * SS) + j) * SS + k];
        t1[idx] = acc;
    }
    __syncthreads();

    // Pass 2: blur along y.
    for (int idx = tid; idx < KS * KS * SS; idx += 256) {
        int k = idx % SS;
        int j = (idx / SS) % KS;
        int i = idx / (SS * KS);
        float acc = 0.f;
        #pragma unroll
        for (int t = 0; t < KS; ++t)
            acc += g[t] * t1[((i * SS) + (j + t)) * SS + k];
        t2[((i * KS) + j) * SS + k] = acc;
    }
    __syncthreads();

    // Pass 3: blur along x + scatter the clipped 9^3 outputs.
    for (int idx = tid; idx < KS * KS * KS; idx += 256) {
        int k = idx % KS;
        int j = (idx / KS) % KS;
        int i = idx / (KS * KS);
        float acc = 0.f;
        #pragma unroll
        for (int t = 0; t < KS; ++t)
            acc += g[t] * t2[((i * KS) + j) * SS + (k + t)];
        int z = pz - RAD + i;
        int y = py - RAD + j;
        int x = px - RAD + k;
        if ((unsigned)z < (unsigned)DIM && (unsigned)y < (unsigned)DIM &&
            (unsigned)x < (unsigned)DIM) {
            out[((z * DIM) + y) * DIM + x] = acc;
        }
    }
}

extern "C" void kernel_launch(void* const* d_in, const int* in_sizes, int n_in,
                              void* d_out, int out_size, void* d_ws, size_t ws_size,
                              hipStream_t stream) {
    const float* vol = (const float*)d_in[0];
    const int*   pts = (const int*)d_in[1];
    float*       out = (float*)d_out;

    const int n   = in_sizes[0];          // 256^3 = 16777216
    const int n4  = n / 4;                // float4 count
    const int npt = in_sizes[1] / 3;      // 6 points

    copy_vol_kernel<<<2048, 256, 0, stream>>>(
        (const float4*)vol, (float4*)out, n4);
    blur_fix_kernel<<<npt, 256, 0, stream>>>(vol, pts, out);
}